// Round 10
// baseline (543.647 us; speedup 1.0000x reference)
//
#include <hip/hip_runtime.h>
#include <hip/hip_bf16.h>
#include <hip/hip_cooperative_groups.h>
namespace cg = cooperative_groups;

#define B_  8
#define L_  384
#define H_  512
#define NH_ 8
#define DH_ 64
#define RRM 768            // rproj rows computed; band uses [1,767]; +1 pad row

typedef short bf16x8 __attribute__((ext_vector_type(8)));
typedef float f32x4  __attribute__((ext_vector_type(4)));
#define MFMA_BF16 __builtin_amdgcn_mfma_f32_16x16x32_bf16

static __device__ __forceinline__ unsigned short f2bf(float f) {
    unsigned u = __builtin_bit_cast(unsigned, f);
    u += 0x7fffu + ((u >> 16) & 1u);           // RNE
    return (unsigned short)(u >> 16);
}
static __device__ __forceinline__ float bf2f(unsigned short s) {
    unsigned u = ((unsigned)s) << 16;
    return __builtin_bit_cast(float, u);
}
typedef unsigned int u32;
static __device__ __forceinline__ void glds16(const void* g, void* l) {
    __builtin_amdgcn_global_load_lds(
        (const __attribute__((address_space(1))) u32*)g,
        (__attribute__((address_space(3))) u32*)l, 16, 0, 0);
}

struct KArgs {
    const float *query, *key, *value, *pe;
    const float *Wq, *Wk, *Wv, *Wr, *Wff;
    const float *bq, *bk, *bv, *br, *bff, *ub, *vb;
    const int* seqlen;
    unsigned short *qbf, *kin, *vin, *pebf;
    unsigned short *Wqb, *Wkb, *Wvb, *Wrb, *Wffb;
    unsigned short *qu, *qv, *kb, *vT, *rp, *Obf;
    float* out;
};

// ---- phase 1: fp32 -> bf16 streaming convert (6272 chunks of 1024 elems) ----
static __device__ __forceinline__ void phase1(const KArgs& a) {
    const float* src[9] = {a.query, a.key, a.value, a.pe, a.Wq, a.Wk, a.Wv, a.Wr, a.Wff};
    unsigned short* dst[9] = {a.qbf, a.kin, a.vin, a.pebf, a.Wqb, a.Wkb, a.Wvb, a.Wrb, a.Wffb};
    const int nch[9] = {1536, 1536, 1536, 384, 256, 256, 256, 256, 256};
    for (int c = blockIdx.x; c < 6272; c += gridDim.x) {
        int cc = c, r = 0;
        while (r < 8 && cc >= nch[r]) { cc -= nch[r]; ++r; }
        const float4 v = ((const float4*)src[r])[cc * 256 + threadIdx.x];
        ushort4 o;
        o.x = f2bf(v.x); o.y = f2bf(v.y); o.z = f2bf(v.z); o.w = f2bf(v.w);
        ((ushort4*)dst[r])[cc * 256 + threadIdx.x] = o;
    }
}

// ---- one 64x64 GEMM tile, K=512, glds16 dbuf staging, XOR-swizzled LDS ----
// z: 0=q(->qu,qv) 1=k 2=vT 3=pe(->rp) 4=FF(->out fp32)
static __device__ void gemm_tile(const KArgs& a, int z, int bx, int by,
                                 unsigned short* sm) {
    const unsigned short *A, *W; const float* bias;
    switch (z) {
        case 0: A = a.qbf;  W = a.Wqb;  bias = a.bq;  break;
        case 1: A = a.kin;  W = a.Wkb;  bias = a.bk;  break;
        case 2: A = a.vin;  W = a.Wvb;  bias = a.bv;  break;
        case 3: A = a.pebf; W = a.Wrb;  bias = a.br;  break;
        default: A = a.Obf; W = a.Wffb; bias = a.bff; break;
    }
    unsigned short* AsF = sm;            // [2][64][64] ushorts
    unsigned short* BsF = sm + 8192;

    const int tid = threadIdx.x;
    const int w = tid >> 6, lane = tid & 63;
    const int quad = lane >> 4, lm = lane & 15;
    const int wr = (w & 1) * 32, wc = (w >> 1) * 32;
    const int sr = lane >> 3, sj = lane & 7;
    const unsigned short* ga = A + (size_t)(by * 64 + w * 16 + sr) * 512 + (sj ^ sr) * 8;
    const unsigned short* gb = W + (size_t)(bx * 64 + w * 16 + sr) * 512 + (sj ^ sr) * 8;

    auto stage = [&](int kc, int buf) {
        #pragma unroll
        for (int t2 = 0; t2 < 2; ++t2) {
            int off = buf * 4096 + (w * 16 + t2 * 8) * 64;
            off = __builtin_amdgcn_readfirstlane(off);
            glds16(ga + kc * 64 + t2 * 8 * 512, &AsF[off]);
            glds16(gb + kc * 64 + t2 * 8 * 512, &BsF[off]);
        }
    };

    f32x4 acc[2][2] = {};
    stage(0, 0);
    for (int kc = 0; kc < 8; ++kc) {
        __syncthreads();                       // drains vmcnt for this buf
        const int buf = kc & 1;
        if (kc < 7) stage(kc + 1, buf ^ 1);
        const int base = buf * 4096;
        #pragma unroll
        for (int ks = 0; ks < 2; ++ks) {
            const int s = (((ks * 4 + quad) ^ (lm & 7))) * 8;
            bf16x8 a0 = *(const bf16x8*)&AsF[base + (wr + lm) * 64 + s];
            bf16x8 a1 = *(const bf16x8*)&AsF[base + (wr + 16 + lm) * 64 + s];
            bf16x8 w0 = *(const bf16x8*)&BsF[base + (wc + lm) * 64 + s];
            bf16x8 w1 = *(const bf16x8*)&BsF[base + (wc + 16 + lm) * 64 + s];
            acc[0][0] = MFMA_BF16(a0, w0, acc[0][0], 0, 0, 0);
            acc[0][1] = MFMA_BF16(a0, w1, acc[0][1], 0, 0, 0);
            acc[1][0] = MFMA_BF16(a1, w0, acc[1][0], 0, 0, 0);
            acc[1][1] = MFMA_BF16(a1, w1, acc[1][1], 0, 0, 0);
        }
    }

    #pragma unroll
    for (int si = 0; si < 2; ++si) {
        #pragma unroll
        for (int sj2 = 0; sj2 < 2; ++sj2) {
            #pragma unroll
            for (int reg = 0; reg < 4; ++reg) {
                const int r = by * 64 + wr + si * 16 + quad * 4 + reg;
                const int c = bx * 64 + wc + sj2 * 16 + lm;
                const float val = acc[si][sj2][reg] + bias[c];
                if (z == 4) {
                    a.out[r * 512 + c] = val;
                } else if (z == 0) {
                    const int bb = r / L_, ii = r - bb * L_;
                    const int h = c >> 6, d = c & 63;
                    const int idx = ((bb * NH_ + h) * L_ + ii) * DH_ + d;
                    a.qu[idx] = f2bf((val + a.ub[c]) * 0.125f);   // pow2: exact
                    a.qv[idx] = f2bf((val + a.vb[c]) * 0.125f);
                } else if (z == 1) {
                    const int bb = r / L_, ii = r - bb * L_;
                    const int h = c >> 6, d = c & 63;
                    a.kb[((bb * NH_ + h) * L_ + ii) * DH_ + d] = f2bf(val);
                } else if (z == 2) {
                    const int bb = r / L_, ii = r - bb * L_;
                    const int h = c >> 6, d = c & 63;
                    a.vT[((bb * NH_ + h) * DH_ + d) * L_ + ii] = f2bf(val);
                } else {
                    a.rp[r * 512 + c] = f2bf(val);
                }
            }
        }
    }
}

static __device__ __forceinline__ void phase2(const KArgs& a, unsigned short* sm) {
    for (int t = blockIdx.x; t < 1248; t += gridDim.x) {
        int z, bx, by;
        if (t < 1152) { z = t / 384; const int rem = t % 384; by = rem >> 3; bx = rem & 7; }
        else          { z = 3;       const int rem = t - 1152; by = rem >> 3; bx = rem & 7; }
        gemm_tile(a, z, bx, by, sm);
    }
}
static __device__ __forceinline__ void phase4(const KArgs& a, unsigned short* sm) {
    for (int t = blockIdx.x; t < 384; t += gridDim.x)
        gemm_tile(a, 4, t & 7, t >> 3, sm);
}

// ---- one fused-attention unit (bh, 32-row i-tile) — verified R8 body ----
#define BTSTR 424
static __device__ void attn_unit(const KArgs& a, int i_t, int bh,
                                 unsigned short* BtP,
                                 float (*mx_red)[2], float (*sm_red)[2]) {
    __syncthreads();                           // BtP reuse across units/phases
    const int lane = threadIdx.x & 63, wv = threadIdx.x >> 6;
    const int quad = lane >> 4, lm = lane & 15;
    const int b = bh >> 3, h = bh & 7;
    const int i0 = i_t * 32;
    const int sl = a.seqlen[b];
    const int msub = wv & 1, nh = wv >> 1;
    const int m_lo = 353 - i0;
    const int i_fr = i0 + msub * 16 + lm;

    {   // Bt tile: Bt[il][n] = qv[i0+il] . rp[m_lo+n], tile-skipped by sl
        const unsigned short* qvr = a.qv + (size_t)(bh * L_ + i_fr) * DH_;
        const bf16x8 av0 = *(const bf16x8*)(qvr + quad * 8);
        const bf16x8 av1 = *(const bf16x8*)(qvr + 32 + quad * 8);
        #pragma unroll
        for (int ns = 0; ns < 13; ++ns) {
            const int ntl = nh * 208 + ns * 16;
            if (ntl <= sl + 30) {
                const int n = ntl + lm;
                const unsigned short* rrow = a.rp + (size_t)(m_lo + n) * 512 + h * 64;
                f32x4 bacc = {};
                bacc = MFMA_BF16(av0, *(const bf16x8*)(rrow + quad * 8), bacc, 0, 0, 0);
                bacc = MFMA_BF16(av1, *(const bf16x8*)(rrow + 32 + quad * 8), bacc, 0, 0, 0);
                #pragma unroll
                for (int reg = 0; reg < 4; ++reg) {
                    const int il = msub * 16 + quad * 4 + reg;
                    BtP[il * BTSTR + n] = f2bf(bacc[reg]);
                }
            }
        }
    }
    const unsigned short* qur = a.qu + (size_t)(bh * L_ + i_fr) * DH_;
    const bf16x8 au0 = *(const bf16x8*)(qur + quad * 8);
    const bf16x8 au1 = *(const bf16x8*)(qur + 32 + quad * 8);
    __syncthreads();

    f32x4 sc[12];
    #pragma unroll
    for (int ns = 0; ns < 12; ++ns) {
        const int jt = nh * 192 + ns * 16;
        if (jt < sl) {
            const unsigned short* krow = a.kb + (size_t)(bh * L_ + jt + lm) * DH_;
            f32x4 acc = {};
            acc = MFMA_BF16(au0, *(const bf16x8*)(krow + quad * 8), acc, 0, 0, 0);
            acc = MFMA_BF16(au1, *(const bf16x8*)(krow + 32 + quad * 8), acc, 0, 0, 0);
            sc[ns] = acc;
        } else {
            sc[ns] = f32x4{-1e30f, -1e30f, -1e30f, -1e30f};
        }
    }
    const int jbase = nh * 192 + lm;
    #pragma unroll
    for (int ns = 0; ns < 12; ++ns) {
        const int j = jbase + ns * 16;
        #pragma unroll
        for (int reg = 0; reg < 4; ++reg) {
            const int il = msub * 16 + quad * 4 + reg;
            float val = -1e30f;
            if (j < sl) val = sc[ns][reg] + bf2f(BtP[il * BTSTR + (j - il + 31)]);
            sc[ns][reg] = val;
        }
    }

    const int il0 = msub * 16 + quad * 4;
    float mx4[4], sm4[4], inv4[4];
    #pragma unroll
    for (int reg = 0; reg < 4; ++reg) {
        float m = sc[0][reg];
        #pragma unroll
        for (int ns = 1; ns < 12; ++ns) m = fmaxf(m, sc[ns][reg]);
        #pragma unroll
        for (int o = 1; o < 16; o <<= 1) m = fmaxf(m, __shfl_xor(m, o));
        mx4[reg] = m;
    }
    if (lm == 0) {
        #pragma unroll
        for (int reg = 0; reg < 4; ++reg) mx_red[il0 + reg][nh] = mx4[reg];
    }
    __syncthreads();
    #pragma unroll
    for (int reg = 0; reg < 4; ++reg)
        mx4[reg] = fmaxf(mx_red[il0 + reg][0], mx_red[il0 + reg][1]);
    #pragma unroll
    for (int reg = 0; reg < 4; ++reg) sm4[reg] = 0.f;
    #pragma unroll
    for (int ns = 0; ns < 12; ++ns) {
        #pragma unroll
        for (int reg = 0; reg < 4; ++reg) {
            const float e = __expf(sc[ns][reg] - mx4[reg]);
            sc[ns][reg] = e;
            sm4[reg] += e;
        }
    }
    #pragma unroll
    for (int reg = 0; reg < 4; ++reg) {
        float s = sm4[reg];
        #pragma unroll
        for (int o = 1; o < 16; o <<= 1) s += __shfl_xor(s, o);
        sm4[reg] = s;
    }
    if (lm == 0) {
        #pragma unroll
        for (int reg = 0; reg < 4; ++reg) sm_red[il0 + reg][nh] = sm4[reg];
    }
    __syncthreads();
    #pragma unroll
    for (int reg = 0; reg < 4; ++reg)
        inv4[reg] = 1.f / (sm_red[il0 + reg][0] + sm_red[il0 + reg][1]);

    #pragma unroll
    for (int ns = 0; ns < 12; ++ns) {
        const int j = jbase + ns * 16;
        #pragma unroll
        for (int reg = 0; reg < 4; ++reg)
            BtP[(il0 + reg) * BTSTR + j] = f2bf(sc[ns][reg] * inv4[reg]);
    }
    __syncthreads();

    {
        const int pr = msub * 16 + lm;
        const int nkc = (sl + 31) >> 5;
        f32x4 oacc[2] = {};
        for (int kc = 0; kc < nkc; ++kc) {
            const bf16x8 af = *(const bf16x8*)&BtP[pr * BTSTR + kc * 32 + quad * 8];
            #pragma unroll
            for (int t = 0; t < 2; ++t) {
                const int n = nh * 32 + t * 16 + lm;
                const unsigned short* vrow = a.vT + (size_t)(bh * DH_ + n) * L_ + kc * 32 + quad * 8;
                oacc[t] = MFMA_BF16(af, *(const bf16x8*)(vrow), oacc[t], 0, 0, 0);
            }
        }
        #pragma unroll
        for (int t = 0; t < 2; ++t) {
            #pragma unroll
            for (int reg = 0; reg < 4; ++reg) {
                const int i = i0 + msub * 16 + quad * 4 + reg;
                const int d = nh * 32 + t * 16 + lm;
                a.Obf[(size_t)(b * L_ + i) * H_ + h * DH_ + d] = f2bf(oacc[t][reg]);
            }
        }
    }
}

static __device__ __forceinline__ void phase3(const KArgs& a, unsigned short* sm,
                                              float (*mx_red)[2], float (*sm_red)[2]) {
    for (int u = blockIdx.x; u < 768; u += gridDim.x)
        attn_unit(a, u % 12, u / 12, sm, mx_red, sm_red);
}

// ---------------- single cooperative kernel ----------------
__global__ __launch_bounds__(256, 2) void fused_all(KArgs a) {
    __shared__ __align__(16) unsigned short smem[16384];   // 32 KB union
    __shared__ float mx_red[32][2], sm_red[32][2];
    cg::grid_group grid = cg::this_grid();

    phase1(a);
    __threadfence(); grid.sync();
    phase2(a, smem);
    __threadfence(); grid.sync();
    phase3(a, smem, mx_red, sm_red);
    __threadfence(); grid.sync();
    phase4(a, smem);
}

// ---------------- fallback (non-cooperative) ----------------
__global__ __launch_bounds__(256, 2) void ph1_k(KArgs a) { phase1(a); }
__global__ __launch_bounds__(256, 2) void ph2_k(KArgs a) {
    __shared__ __align__(16) unsigned short smem[16384];
    phase2(a, smem);
}
__global__ __launch_bounds__(256, 2) void ph3_k(KArgs a) {
    __shared__ __align__(16) unsigned short smem[16384];
    __shared__ float mx_red[32][2], sm_red[32][2];
    phase3(a, smem, mx_red, sm_red);
}
__global__ __launch_bounds__(256, 2) void ph4_k(KArgs a) {
    __shared__ __align__(16) unsigned short smem[16384];
    phase4(a, smem);
}

extern "C" void kernel_launch(void* const* d_in, const int* in_sizes, int n_in,
                              void* d_out, int out_size, void* d_ws, size_t ws_size,
                              hipStream_t stream) {
    KArgs ka;
    ka.key    = (const float*)d_in[0];
    ka.query  = (const float*)d_in[1];
    ka.value  = (const float*)d_in[2];
    ka.seqlen = (const int*)d_in[3];
    ka.pe     = (const float*)d_in[4];
    ka.Wk     = (const float*)d_in[5];
    ka.bk     = (const float*)d_in[6];
    ka.Wq     = (const float*)d_in[7];
    ka.bq     = (const float*)d_in[8];
    ka.Wv     = (const float*)d_in[9];
    ka.bv     = (const float*)d_in[10];
    ka.Wr     = (const float*)d_in[11];
    ka.br     = (const float*)d_in[12];
    ka.ub     = (const float*)d_in[13];
    ka.vb     = (const float*)d_in[14];
    ka.Wff    = (const float*)d_in[15];
    ka.bff    = (const float*)d_in[16];
    ka.out    = (float*)d_out;

    const size_t nTok = (size_t)B_ * L_ * H_;    // 1,572,864
    const size_t nPe  = (size_t)RRM * H_;        // 393,216
    const size_t nW   = (size_t)H_ * H_;         // 262,144
    unsigned short* p = (unsigned short*)d_ws;
    ka.qbf  = p; p += nTok;                      // aliased as Obf after proj
    ka.kin  = p; p += nTok;
    ka.vin  = p; p += nTok;
    ka.pebf = p; p += nPe;
    ka.Wqb  = p; p += nW;
    ka.Wkb  = p; p += nW;
    ka.Wvb  = p; p += nW;
    ka.Wrb  = p; p += nW;
    ka.Wffb = p; p += nW;
    ka.qu   = p; p += nTok;
    ka.qv   = p; p += nTok;
    ka.kb   = p; p += nTok;
    ka.vT   = p; p += nTok;
    ka.rp   = p; p += nPe + 512;                 // +1 pad row (masked corner)
    ka.Obf  = ka.qbf;                            // disjoint lifetime

    void* params[] = { &ka };
    hipError_t e = hipLaunchCooperativeKernel((const void*)fused_all, dim3(512),
                                              dim3(256), params, 0, stream);
    if (e != hipSuccess) {                       // capture-safe fallback
        (void)hipGetLastError();
        ph1_k<<<512, 256, 0, stream>>>(ka);
        ph2_k<<<512, 256, 0, stream>>>(ka);
        ph3_k<<<768, 256, 0, stream>>>(ka);
        ph4_k<<<384, 256, 0, stream>>>(ka);
    }
}